// Round 5
// baseline (311.810 us; speedup 1.0000x reference)
//
#include <hip/hip_runtime.h>
#include <hip/hip_fp16.h>
#include <math.h>

constexpr int N_ENT = 20000;
constexpr int N_REL = 500;
constexpr int NE    = 300000;   // entity triplets
constexpr int NER   = 50000;    // relation triplets
constexpr int MPE   = 20096;    // 157*128 (padded entity rows)
constexpr int MPS   = 20608;    // 161*128 (padded self+rel rows)
constexpr float EPSF = 1e-16f;

__device__ __forceinline__ float leaky(float x) { return x > 0.f ? x : 0.2f * x; }

typedef __attribute__((ext_vector_type(8))) _Float16 f16x8;
typedef __attribute__((ext_vector_type(4))) float f32x4;

struct __align__(8) h2p { __half2 a, g; };

// ---------------------------------------------------------------- MFMA fp16 GEMM
// C[M,N] = A[M,K]fp16 @ B[N,K]fp16^T + bias.  BM=128, BN=64, BK=32, 4 waves.
__global__ __launch_bounds__(256) void k_hgemm(
    const _Float16* __restrict__ A,
    const _Float16* __restrict__ B,
    const float* __restrict__ bias,
    __half* __restrict__ O16, float* __restrict__ O32,
    int M, int N, int K, int ldo)
{
    __shared__ __align__(16) _Float16 lA[4 * 128 * 8];   // [kgrp][row][8]
    __shared__ __align__(16) _Float16 lB[4 * 64 * 8];    // [kgrp][row][8]
    int tid = threadIdx.x;
    int m0 = blockIdx.y * 128, n0 = blockIdx.x * 64;
    int l = tid & 63, w = tid >> 6;
    int wr = w >> 1, wc = w & 1;
    int kq = l >> 4, lr = l & 15;

    int sA0 = tid, sA1 = tid + 256;
    const uint4* pA0 = (const uint4*)(A + (size_t)(m0 + (sA0 & 127)) * K) + (sA0 >> 7);
    const uint4* pA1 = (const uint4*)(A + (size_t)(m0 + (sA1 & 127)) * K) + (sA1 >> 7);
    const uint4* pB  = (const uint4*)(B + (size_t)(n0 + (tid & 63)) * K) + (tid >> 6);

    f32x4 acc[4][2] = {};
    int nk = K >> 5;
    uint4 va0 = pA0[0], va1 = pA1[0], vb = pB[0];
    for (int t = 0; t < nk; ++t) {
        ((uint4*)lA)[sA0] = va0;
        ((uint4*)lA)[sA1] = va1;
        ((uint4*)lB)[tid] = vb;
        __syncthreads();
        if (t + 1 < nk) {
            va0 = pA0[(t + 1) * 4];
            va1 = pA1[(t + 1) * 4];
            vb  = pB[(t + 1) * 4];
        }
        f16x8 bf0 = *(const f16x8*)&lB[(kq * 64 + wc * 32 + lr) * 8];
        f16x8 bf1 = *(const f16x8*)&lB[(kq * 64 + wc * 32 + 16 + lr) * 8];
#pragma unroll
        for (int fm = 0; fm < 4; ++fm) {
            f16x8 af = *(const f16x8*)&lA[(kq * 128 + wr * 64 + fm * 16 + lr) * 8];
            acc[fm][0] = __builtin_amdgcn_mfma_f32_16x16x32_f16(af, bf0, acc[fm][0], 0, 0, 0);
            acc[fm][1] = __builtin_amdgcn_mfma_f32_16x16x32_f16(af, bf1, acc[fm][1], 0, 0, 0);
        }
        __syncthreads();
    }
    int gn0 = n0 + wc * 32 + lr;
    int gn1 = gn0 + 16;
    float bc0 = (bias && gn0 < N) ? bias[gn0] : 0.f;
    float bc1 = (bias && gn1 < N) ? bias[gn1] : 0.f;
#pragma unroll
    for (int fm = 0; fm < 4; ++fm) {
#pragma unroll
        for (int j = 0; j < 4; ++j) {
            int gm = m0 + wr * 64 + fm * 16 + kq * 4 + j;
            if (gm >= M) continue;
            float v0 = acc[fm][0][j] + bc0;
            float v1 = acc[fm][1][j] + bc1;
            if (O16) {
                if (gn0 < N) O16[(size_t)gm * ldo + gn0] = __float2half_rn(v0);
                if (gn1 < N) O16[(size_t)gm * ldo + gn1] = __float2half_rn(v1);
            } else {
                if (gn0 < N) O32[(size_t)gm * ldo + gn0] = v0;
                if (gn1 < N) O32[(size_t)gm * ldo + gn1] = v1;
            }
        }
    }
}

// ---------------------------------------------------------------- GEMM 64x64 fp32 (rel-side, tiny)
__global__ __launch_bounds__(256) void k_gemm(
    const float* __restrict__ A,
    const float* __restrict__ B, int ldb,
    const float* __restrict__ bias,
    float* __restrict__ C,
    int M, int N, int K)
{
    __shared__ float As[32][65];
    __shared__ float Bs[32][65];
    int tid = threadIdx.x;
    int m0 = blockIdx.y * 64, n0 = blockIdx.x * 64;
    int tx = tid & 15, ty = tid >> 4;
    float acc[4][4] = {};
    for (int k0 = 0; k0 < K; k0 += 32) {
#pragma unroll
        for (int t = 0; t < 8; ++t) {
            int idx = t * 256 + tid;
            int m = idx >> 5, k = idx & 31;
            int gk = k0 + k;
            int gm = m0 + m;
            As[k][m] = (gm < M && gk < K) ? A[(size_t)gm * K + gk] : 0.f;
            int gn = n0 + m;
            Bs[k][m] = (gn < N && gk < K) ? B[(size_t)gn * ldb + gk] : 0.f;
        }
        __syncthreads();
#pragma unroll
        for (int k = 0; k < 32; ++k) {
            float a[4], b[4];
#pragma unroll
            for (int i = 0; i < 4; ++i) a[i] = As[k][ty * 4 + i];
#pragma unroll
            for (int j = 0; j < 4; ++j) b[j] = Bs[k][tx * 4 + j];
#pragma unroll
            for (int i = 0; i < 4; ++i)
#pragma unroll
                for (int j = 0; j < 4; ++j)
                    acc[i][j] = fmaf(a[i], b[j], acc[i][j]);
        }
        __syncthreads();
    }
#pragma unroll
    for (int i = 0; i < 4; ++i) {
        int gm = m0 + ty * 4 + i;
        if (gm >= M) continue;
#pragma unroll
        for (int j = 0; j < 4; ++j) {
            int gn = n0 + tx * 4 + j;
            if (gn >= N) continue;
            float v = acc[i][j];
            if (bias) v += bias[gn];
            C[(size_t)gm * N + gn] = v;
        }
    }
}

// ---------------------------------------------------------------- mega-pack + fp16 converts + zero counters
// E-layer N=512 layout: [Pt(128) | X: att/agg pair-interleaved (256) | Res(128)]
//   X col m (0..255): i=m>>2, sub=m&3: sub<2 -> att col 2i+sub ; sub>=2 -> agg col 2i+sub-2
// F (self/rel) N=512: per-layer 256-block with the same X interleave.
__global__ void k_pack_all(
    const float* __restrict__ emb_ent,
    const float* __restrict__ Wa_e, const float* __restrict__ ba_e,
    const float* __restrict__ Wg_e, const float* __restrict__ bg_e,
    const float* __restrict__ Wres_e, const float* __restrict__ bres_e,
    const float* __restrict__ Wa_r, const float* __restrict__ ba_r,
    const float* __restrict__ Wg_r, const float* __restrict__ bg_r,
    const float* __restrict__ Wres_r, const float* __restrict__ bres_r,
    const float* __restrict__ Wp1e, const float* __restrict__ Wp2e,
    _Float16* __restrict__ embh,
    _Float16* __restrict__ Bp1f, float* __restrict__ bias1,
    _Float16* __restrict__ Bp2f,
    float* __restrict__ Bp3, float* __restrict__ bias3,
    _Float16* __restrict__ Bpe1, _Float16* __restrict__ Bpe2,
    int* __restrict__ cnt)
{
    int gid = blockIdx.x * 256 + threadIdx.x;
    if (gid < N_ENT * 32) embh[gid] = (_Float16)emb_ent[gid];
    if (gid < 2 * 512 * 128) {          // Bp1f[l][512][128]
        int l = gid / (512 * 128), rem = gid % (512 * 128);
        int row = rem >> 7, k = rem & 127;
        const float* Wa = Wa_e + (size_t)l * 128 * 320;
        const float* Wg = Wg_e + (size_t)l * 128 * 192;
        const float* Wr = Wres_e + (size_t)l * 128 * 128;
        float v;
        if (row < 128) v = Wa[row * 320 + k];
        else if (row < 384) {
            int m = row - 128, i = m >> 2, sub = m & 3;
            v = (sub < 2) ? Wa[(2 * i + sub) * 320 + 128 + k]
                          : Wg[(2 * i + sub - 2) * 192 + k];
        } else v = Wr[(row - 384) * 128 + k];
        Bp1f[gid] = (_Float16)v;
    }
    if (gid < 512 * 64) {               // Bp2f[l*256 + m][64], X interleave
        int row = gid >> 6, k = gid & 63;
        int l = row >> 8, m = row & 255;
        int i = m >> 2, sub = m & 3;
        const float* Wa = Wa_e + (size_t)l * 128 * 320;
        const float* Wg = Wg_e + (size_t)l * 128 * 192;
        float v = (sub < 2) ? Wa[(2 * i + sub) * 320 + 256 + k]
                            : Wg[(2 * i + sub - 2) * 192 + 128 + k];
        Bp2f[gid] = (_Float16)v;
    }
    if (gid < 2 * 256 * 64) {           // Bp3[l][256][64] fp32: Wa(2 slabs) | Wg | Wres
        int l = gid / (256 * 64), rem = gid % (256 * 64);
        int row = rem >> 6, k = rem & 63;
        const float* Wa = Wa_r + (size_t)l * 64 * 128;
        const float* Wg = Wg_r + (size_t)l * 64 * 64;
        const float* Wr = Wres_r + (size_t)l * 64 * 64;
        float v;
        if (row < 64) v = Wa[row * 128 + k];
        else if (row < 128) v = Wa[(row - 64) * 128 + 64 + k];
        else if (row < 192) v = Wg[(row - 128) * 64 + k];
        else v = Wr[(row - 192) * 64 + k];
        Bp3[gid] = v;
    }
    if (gid < 128 * 32) Bpe1[gid] = (_Float16)Wp1e[gid];
    if (gid < 64 * 128) {               // Bpe2 zero-padded to 64 rows
        int row = gid >> 7, k = gid & 127;
        Bpe2[gid] = (row < 32) ? (_Float16)Wp2e[row * 128 + k] : (_Float16)0.f;
    }
    if (gid < 2 * 512) {
        int l = gid / 512, j = gid % 512;
        float v;
        if (j < 128) v = ba_e[l * 128 + j];
        else if (j < 384) {
            int m = j - 128, i = m >> 2, sub = m & 3;
            v = (sub < 2) ? 0.f : bg_e[l * 128 + 2 * i + sub - 2];
        } else v = bres_e[l * 128 + j - 384];
        bias1[gid] = v;
    }
    if (gid < 2 * 256) {
        int l = gid / 256, j = gid % 256;
        float v;
        if (j < 64) v = ba_r[l * 64 + j];
        else if (j < 128) v = 0.f;
        else if (j < 192) v = bg_r[l * 64 + j - 128];
        else v = bres_r[l * 64 + j - 192];
        bias3[gid] = v;
    }
    if (gid < N_ENT + N_REL) cnt[gid] = 0;
}

// ---------------------------------------------------------------- CSR build
__global__ void k_count2(const int* __restrict__ tr, const int* __restrict__ rt,
                         int* __restrict__ cntE, int* __restrict__ cntR) {
    int i = blockIdx.x * 256 + threadIdx.x;
    if (i < NE) atomicAdd(&cntE[tr[i * 3 + 2]], 1);
    else if (i < NE + NER) atomicAdd(&cntR[rt[(i - NE) * 3 + 0]], 1);
}

// single-pass scans: block 0 -> entities (20 elems/thread), block 1 -> relations
__global__ __launch_bounds__(1024) void k_scan2(
    const int* __restrict__ cntE, int* __restrict__ offsE, int* __restrict__ curE,
    const int* __restrict__ cntR, int* __restrict__ offsR, int* __restrict__ curR)
{
    __shared__ int wsum[16];
    int tid = threadIdx.x;
    int lane = tid & 63, wid = tid >> 6;
    if (blockIdx.x == 0) {
        constexpr int C = 20;
        int loc[C];
        int base = tid * C;
        int sum = 0;
#pragma unroll
        for (int j = 0; j < C; ++j) {
            int e = base + j;
            int v = (e < N_ENT) ? cntE[e] : 0;
            loc[j] = sum;
            sum += v;
        }
        int x = sum;
#pragma unroll
        for (int o = 1; o < 64; o <<= 1) {
            int y = __shfl_up(x, o, 64);
            if (lane >= o) x += y;
        }
        if (lane == 63) wsum[wid] = x;
        __syncthreads();
        if (wid == 0 && lane < 16) {
            int wv = wsum[lane];
#pragma unroll
            for (int o = 1; o < 16; o <<= 1) {
                int y = __shfl_up(wv, o, 64);
                if (lane >= o) wv += y;
            }
            wsum[lane] = wv;
        }
        __syncthreads();
        int excl = (wid ? wsum[wid - 1] : 0) + x - sum;
#pragma unroll
        for (int j = 0; j < C; ++j) {
            int e = base + j;
            if (e < N_ENT) { int o2 = excl + loc[j]; offsE[e] = o2; curE[e] = o2; }
        }
        if (tid == 1023) offsE[N_ENT] = excl + sum;
    } else {
        int v = (tid < N_REL) ? cntR[tid] : 0;
        int x = v;
#pragma unroll
        for (int o = 1; o < 64; o <<= 1) {
            int y = __shfl_up(x, o, 64);
            if (lane >= o) x += y;
        }
        if (lane == 63) wsum[wid] = x;
        __syncthreads();
        if (wid == 0 && lane < 16) {
            int wv = wsum[lane];
#pragma unroll
            for (int o = 1; o < 16; o <<= 1) {
                int y = __shfl_up(wv, o, 64);
                if (lane >= o) wv += y;
            }
            wsum[lane] = wv;
        }
        __syncthreads();
        int excl = (wid ? wsum[wid - 1] : 0) + x - v;
        if (tid < N_REL) { offsR[tid] = excl; curR[tid] = excl; }
        if (tid == 1023) offsR[N_REL] = excl + v;
    }
}

__global__ void k_scatter2(const int* __restrict__ tr, const int* __restrict__ rt,
                           int* __restrict__ curE, int* __restrict__ curR,
                           int2* __restrict__ hrE, int2* __restrict__ tbR) {
    int i = blockIdx.x * 256 + threadIdx.x;
    if (i < NE) {
        int pos = atomicAdd(&curE[tr[i * 3 + 2]], 1);
        hrE[pos] = make_int2(tr[i * 3 + 0], tr[i * 3 + 1]);
    } else if (i < NE + NER) {
        int e = i - NE;
        int pos = atomicAdd(&curR[rt[e * 3 + 0]], 1);
        tbR[pos] = make_int2(rt[e * 3 + 1], rt[e * 3 + 2]);
    }
}

// ---------------------------------------------------------------- rel layer (1 block/node, 4 waves split edges)
__global__ __launch_bounds__(256) void k_rel_fused(
    const float* __restrict__ AR,     // 500x256: Ah+ba | At | G+bg | R(res)
    const float* __restrict__ vec,    // 64
    const float* __restrict__ abin,   // 10x8
    const int2* __restrict__ tbR,
    const int* __restrict__ offs,
    float* __restrict__ xout)         // 500x64
{
    __shared__ float sS[4][64], sA[4][64];
    int n = blockIdx.x;
    int w = threadIdx.x >> 6, col = threadIdx.x & 63;
    int head = col >> 3;
    float ah = AR[n * 256 + col];
    float vc = vec[col];
    int e0 = offs[n], e1 = offs[n + 1];
    float s = 0.f, acc = 0.f;
    for (int i = e0 + w * 4; i < e1; i += 16) {
        int i0 = i;
        int i1 = (i + 1 < e1) ? i + 1 : e1 - 1;
        int i2 = (i + 2 < e1) ? i + 2 : e1 - 1;
        int i3 = (i + 3 < e1) ? i + 3 : e1 - 1;
        int2 t0 = tbR[i0], t1 = tbR[i1], t2 = tbR[i2], t3 = tbR[i3];
        float v0 = leaky(ah + AR[t0.x * 256 + 64 + col]) * vc;
        float v1 = leaky(ah + AR[t1.x * 256 + 64 + col]) * vc;
        float v2 = leaky(ah + AR[t2.x * 256 + 64 + col]) * vc;
        float v3 = leaky(ah + AR[t3.x * 256 + 64 + col]) * vc;
        float g0 = AR[t0.x * 256 + 128 + col];
        float g1 = AR[t1.x * 256 + 128 + col];
        float g2 = AR[t2.x * 256 + 128 + col];
        float g3 = AR[t3.x * 256 + 128 + col];
#pragma unroll
        for (int o = 1; o < 8; o <<= 1) {
            v0 += __shfl_xor(v0, o, 64); v1 += __shfl_xor(v1, o, 64);
            v2 += __shfl_xor(v2, o, 64); v3 += __shfl_xor(v3, o, 64);
        }
        float w0 = __expf(v0 + abin[t0.y * 8 + head]);
        float w1 = (i + 1 < e1) ? __expf(v1 + abin[t1.y * 8 + head]) : 0.f;
        float w2 = (i + 2 < e1) ? __expf(v2 + abin[t2.y * 8 + head]) : 0.f;
        float w3 = (i + 3 < e1) ? __expf(v3 + abin[t3.y * 8 + head]) : 0.f;
        s += (w0 + w1) + (w2 + w3);
        acc = fmaf(w0, g0, acc); acc = fmaf(w1, g1, acc);
        acc = fmaf(w2, g2, acc); acc = fmaf(w3, g3, acc);
    }
    sS[w][col] = s; sA[w][col] = acc;
    __syncthreads();
    if (w == 0) {
        s = (sS[0][col] + sS[1][col]) + (sS[2][col] + sS[3][col]);
        acc = (sA[0][col] + sA[1][col]) + (sA[2][col] + sA[3][col]);
        float upd = acc / (s + EPSF);
        xout[n * 64 + col] = fmaxf(AR[n * 256 + 192 + col] + upd, 0.f);
    }
}

// ---------------------------------------------------------------- self_rel -> SRsrc fp16 (+ xr tail)
__global__ __launch_bounds__(256) void k_self_rel(
    const float* __restrict__ xr, const int2* __restrict__ hrE,
    const int* __restrict__ offs, __half* __restrict__ SRsrc)
{
    int gid = blockIdx.x * 256 + threadIdx.x;
    if (gid < N_ENT * 64) {
        int n = gid >> 6, col = gid & 63;
        int e0 = offs[n], e1 = offs[n + 1];
        float acc = 0.f;
        for (int i = e0; i < e1; i += 4) {
            int i1 = (i + 1 < e1) ? i + 1 : e1 - 1;
            int i2 = (i + 2 < e1) ? i + 2 : e1 - 1;
            int i3 = (i + 3 < e1) ? i + 3 : e1 - 1;
            int r0 = hrE[i].y, r1 = hrE[i1].y, r2 = hrE[i2].y, r3 = hrE[i3].y;
            float a0 = xr[r0 * 64 + col];
            float a1 = (i + 1 < e1) ? xr[r1 * 64 + col] : 0.f;
            float a2 = (i + 2 < e1) ? xr[r2 * 64 + col] : 0.f;
            float a3 = (i + 3 < e1) ? xr[r3 * 64 + col] : 0.f;
            acc += (a0 + a1) + (a2 + a3);
        }
        SRsrc[(size_t)n * 64 + col] = __float2half_rn(acc / ((float)(e1 - e0) + EPSF));
    } else {
        int j = gid - N_ENT * 64;   // < N_REL*64
        SRsrc[(size_t)N_ENT * 64 + j] = __float2half_rn(xr[j]);
    }
}

// ---------------------------------------------------------------- ent layer (fused; pair-interleaved tables)
// E16 row [512]: Pt+ba (128) | X att/agg pairs (256) | Res (128)
// Fl = F16 + l*256; rows [512]: per-layer X att/agg pairs (256) x 2 layers
__global__ __launch_bounds__(256) void k_ent_fused(
    const __half* __restrict__ E16,
    const __half* __restrict__ Fl,
    const float* __restrict__ vec,    // 128
    const int2* __restrict__ hrE,
    const int* __restrict__ offs,
    __half* __restrict__ xout)        // [MPE][128] fp16
{
    int gid = blockIdx.x * 256 + threadIdx.x;
    int n = gid >> 6;
    int l = threadIdx.x & 63;
    int c2 = l << 1;
    const __half2* En = (const __half2*)(E16 + (size_t)n * 512);
    float2 pt = __half22float2(En[l]);
    float2 vc = *(const float2*)&vec[c2];
    h2p sp = *(const h2p*)(E16 + (size_t)n * 512 + 128 + 4 * l);
    h2p fp_ = *(const h2p*)(Fl + (size_t)n * 512 + 4 * l);
    float2 rr = __half22float2(En[192 + l]);
    float2 sa = __half22float2(sp.a), sg = __half22float2(sp.g);
    float2 fa = __half22float2(fp_.a), fg = __half22float2(fp_.g);
    float vs = leaky(pt.x + sa.x + fa.x) * vc.x + leaky(pt.y + sa.y + fa.y) * vc.y;
#pragma unroll
    for (int o = 1; o < 8; o <<= 1) vs += __shfl_xor(vs, o, 64);
    float ws = __expf(vs);
    float s = ws;
    float accx = ws * (sg.x + fg.x);
    float accy = ws * (sg.y + fg.y);
    int e0 = offs[n], e1 = offs[n + 1];
    for (int i = e0; i < e1; i += 4) {
        int i1 = (i + 1 < e1) ? i + 1 : e1 - 1;
        int i2 = (i + 2 < e1) ? i + 2 : e1 - 1;
        int i3 = (i + 3 < e1) ? i + 3 : e1 - 1;
        int2 ev0 = hrE[i], ev1 = hrE[i1], ev2 = hrE[i2], ev3 = hrE[i3];
        h2p p0 = *(const h2p*)(E16 + (size_t)ev0.x * 512 + 128 + 4 * l);
        h2p p1 = *(const h2p*)(E16 + (size_t)ev1.x * 512 + 128 + 4 * l);
        h2p p2 = *(const h2p*)(E16 + (size_t)ev2.x * 512 + 128 + 4 * l);
        h2p p3 = *(const h2p*)(E16 + (size_t)ev3.x * 512 + 128 + 4 * l);
        h2p q0 = *(const h2p*)(Fl + (size_t)(N_ENT + ev0.y) * 512 + 4 * l);
        h2p q1 = *(const h2p*)(Fl + (size_t)(N_ENT + ev1.y) * 512 + 4 * l);
        h2p q2 = *(const h2p*)(Fl + (size_t)(N_ENT + ev2.y) * 512 + 4 * l);
        h2p q3 = *(const h2p*)(Fl + (size_t)(N_ENT + ev3.y) * 512 + 4 * l);
        float2 a0 = __half22float2(p0.a), r0 = __half22float2(q0.a);
        float2 a1 = __half22float2(p1.a), r1 = __half22float2(q1.a);
        float2 a2 = __half22float2(p2.a), r2 = __half22float2(q2.a);
        float2 a3 = __half22float2(p3.a), r3 = __half22float2(q3.a);
        float v0 = leaky(pt.x + a0.x + r0.x) * vc.x + leaky(pt.y + a0.y + r0.y) * vc.y;
        float v1 = leaky(pt.x + a1.x + r1.x) * vc.x + leaky(pt.y + a1.y + r1.y) * vc.y;
        float v2 = leaky(pt.x + a2.x + r2.x) * vc.x + leaky(pt.y + a2.y + r2.y) * vc.y;
        float v3 = leaky(pt.x + a3.x + r3.x) * vc.x + leaky(pt.y + a3.y + r3.y) * vc.y;
#pragma unroll
        for (int o = 1; o < 8; o <<= 1) {
            v0 += __shfl_xor(v0, o, 64); v1 += __shfl_xor(v1, o, 64);
            v2 += __shfl_xor(v2, o, 64); v3 += __shfl_xor(v3, o, 64);
        }
        float w0 = __expf(v0);
        float w1 = (i + 1 < e1) ? __expf(v1) : 0.f;
        float w2 = (i + 2 < e1) ? __expf(v2) : 0.f;
        float w3 = (i + 3 < e1) ? __expf(v3) : 0.f;
        s += (w0 + w1) + (w2 + w3);
        float2 g0 = __half22float2(p0.g), u0 = __half22float2(q0.g);
        float2 g1 = __half22float2(p1.g), u1 = __half22float2(q1.g);
        float2 g2 = __half22float2(p2.g), u2 = __half22float2(q2.g);
        float2 g3 = __half22float2(p3.g), u3 = __half22float2(q3.g);
        accx = fmaf(w0, g0.x + u0.x, accx); accy = fmaf(w0, g0.y + u0.y, accy);
        accx = fmaf(w1, g1.x + u1.x, accx); accy = fmaf(w1, g1.y + u1.y, accy);
        accx = fmaf(w2, g2.x + u2.x, accx); accy = fmaf(w2, g2.y + u2.y, accy);
        accx = fmaf(w3, g3.x + u3.x, accx); accy = fmaf(w3, g3.y + u3.y, accy);
    }
    float inv = 1.f / (s + EPSF);
    float ox = fmaxf(rr.x + accx * inv, 0.f);
    float oy = fmaxf(rr.y + accy * inv, 0.f);
    ((__half2*)(xout + (size_t)n * 128))[l] = __floats2half2_rn(ox, oy);
}

// ---------------------------------------------------------------- launch
extern "C" void kernel_launch(void* const* d_in, const int* in_sizes, int n_in,
                              void* d_out, int out_size, void* d_ws, size_t ws_size,
                              hipStream_t stream) {
    const float* emb_ent      = (const float*)d_in[0];
    const float* emb_rel      = (const float*)d_in[1];
    const int*   tr           = (const int*)d_in[2];
    const int*   rt           = (const int*)d_in[3];
    const float* ent_proj1_W  = (const float*)d_in[4];
    const float* ent_proj1_b  = (const float*)d_in[5];
    const float* rel_proj1_W  = (const float*)d_in[6];
    const float* rel_proj1_b  = (const float*)d_in[7];
    const float* rel_attn_W   = (const float*)d_in[8];
    const float* rel_attn_b   = (const float*)d_in[9];
    const float* rel_attn_bin = (const float*)d_in[10];
    const float* rel_attn_vec = (const float*)d_in[11];
    const float* rel_aggr_W   = (const float*)d_in[12];
    const float* rel_aggr_b   = (const float*)d_in[13];
    const float* res_rel_W    = (const float*)d_in[14];
    const float* res_rel_b    = (const float*)d_in[15];
    const float* ent_attn_W   = (const float*)d_in[16];
    const float* ent_attn_b   = (const float*)d_in[17];
    const float* ent_attn_vec = (const float*)d_in[18];
    const float* ent_aggr_W   = (const float*)d_in[19];
    const float* ent_aggr_b   = (const float*)d_in[20];
    const float* res_ent_W    = (const float*)d_in[21];
    const float* res_ent_b    = (const float*)d_in[22];
    const float* ent_proj2_W  = (const float*)d_in[23];
    const float* ent_proj2_b  = (const float*)d_in[24];
    const float* rel_proj2_W  = (const float*)d_in[25];
    const float* rel_proj2_b  = (const float*)d_in[26];
    float* out = (float*)d_out;

    // workspace carve (256B aligned)
    size_t off = 0;
    char* base = (char*)d_ws;
    auto alloc = [&](size_t nbytes) -> void* {
        void* p = base + off;
        off += (nbytes + 255) & ~(size_t)255;
        return p;
    };
    _Float16* embh  = (_Float16*)alloc((size_t)MPE * 32 * 2);
    __half*   xea   = (__half*)alloc((size_t)MPE * 128 * 2);
    __half*   xeb   = (__half*)alloc((size_t)MPE * 128 * 2);
    __half*   E16   = (__half*)alloc((size_t)MPE * 512 * 2);
    __half*   F16   = (__half*)alloc((size_t)MPS * 512 * 2);
    __half*   SRsrc = (__half*)alloc((size_t)MPS * 64 * 2);
    float*    xr0   = (float*)alloc((size_t)N_REL * 64 * 4);
    float*    xr1   = (float*)alloc((size_t)N_REL * 64 * 4);
    float*    AR    = (float*)alloc((size_t)N_REL * 256 * 4);
    _Float16* Bp1f  = (_Float16*)alloc((size_t)2 * 512 * 128 * 2);
    float*    bias1 = (float*)alloc(2 * 512 * 4);
    _Float16* Bp2f  = (_Float16*)alloc(512 * 64 * 2);
    float*    Bp3   = (float*)alloc((size_t)2 * 256 * 64 * 4);
    float*    bias3 = (float*)alloc(2 * 256 * 4);
    _Float16* Bpe1  = (_Float16*)alloc(128 * 32 * 2);
    _Float16* Bpe2  = (_Float16*)alloc(64 * 128 * 2);
    int*  cnt   = (int*)alloc((size_t)(N_ENT + N_REL) * 4);
    int*  cntE  = cnt;
    int*  cntR  = cnt + N_ENT;
    int*  offsE = (int*)alloc((N_ENT + 1) * 4);
    int*  offsR = (int*)alloc((N_REL + 1) * 4);
    int*  curE  = (int*)alloc(N_ENT * 4);
    int*  curR  = (int*)alloc(N_REL * 4);
    int2* hrE   = (int2*)alloc((size_t)NE * 8);
    int2* tbR   = (int2*)alloc((size_t)NER * 8);

    auto gemm64 = [&](const float* A, const float* B, int ldb, const float* bias,
                      float* C, int M, int N, int K) {
        dim3 g((N + 63) / 64, (M + 63) / 64);
        k_gemm<<<g, 256, 0, stream>>>(A, B, ldb, bias, C, M, N, K);
    };
    auto hgemm = [&](const _Float16* A, const _Float16* B, const float* bias,
                     __half* O16, float* O32, int M, int N, int K, int ldo, int gridN) {
        dim3 g(gridN, (M + 127) / 128);
        k_hgemm<<<g, 256, 0, stream>>>(A, B, bias, O16, O32, M, N, K, ldo);
    };

    // 1. pack all weights, convert emb_ent to fp16, zero counters
    k_pack_all<<<(N_ENT * 32 + 255) / 256, 256, 0, stream>>>(
        emb_ent,
        ent_attn_W, ent_attn_b, ent_aggr_W, ent_aggr_b, res_ent_W, res_ent_b,
        rel_attn_W, rel_attn_b, rel_aggr_W, rel_aggr_b, res_rel_W, res_rel_b,
        ent_proj1_W, ent_proj2_W,
        embh, Bp1f, bias1, Bp2f, Bp3, bias3, Bpe1, Bpe2, cnt);

    // 2-4. CSR builds
    k_count2<<<(NE + NER + 255) / 256, 256, 0, stream>>>(tr, rt, cntE, cntR);
    k_scan2<<<2, 1024, 0, stream>>>(cntE, offsE, curE, cntR, offsR, curR);
    k_scatter2<<<(NE + NER + 255) / 256, 256, 0, stream>>>(tr, rt, curE, curR, hrE, tbR);

    // 5-6. input projections
    hgemm(embh, Bpe1, ent_proj1_b, xea, nullptr, N_ENT, 128, 32, 128, 2);
    gemm64(emb_rel, rel_proj1_W, 16, rel_proj1_b, xr0, N_REL, 64, 16);

    // 7. relation layers (GEMM N=256: Ah|At|G|R; fused does +res+relu)
    for (int l = 0; l < 2; ++l) {
        const float* xin = l ? xr1 : xr0;
        float* xout = l ? xr0 : xr1;
        gemm64(xin, Bp3 + (size_t)l * 256 * 64, 64, bias3 + l * 256, AR, N_REL, 256, 64);
        k_rel_fused<<<N_REL, 256, 0, stream>>>(
            AR, rel_attn_vec + (size_t)l * 64, rel_attn_bin + (size_t)l * 80,
            tbR, offsR, xout);
    }
    // final x_rel = xr0

    // 8. self_rel -> SRsrc fp16 (+ xr tail rows)
    k_self_rel<<<((N_ENT + N_REL) * 64) / 256, 256, 0, stream>>>(xr0, hrE, offsE, SRsrc);

    // 9. merged SS/RR GEMM for both layers -> F16 fp16 (interleaved X layout)
    hgemm((const _Float16*)SRsrc, Bp2f, nullptr, F16, nullptr, N_ENT + N_REL, 512, 64, 512, 8);

    // 10. entity layers (GEMM N=512: Pt|X|R; fused does +res+relu)
    for (int l = 0; l < 2; ++l) {
        const __half* xin = l ? xeb : xea;
        __half* xout = l ? xea : xeb;
        hgemm((const _Float16*)xin, Bp1f + (size_t)l * 512 * 128, bias1 + l * 512,
              E16, nullptr, N_ENT, 512, 128, 512, 8);
        k_ent_fused<<<(N_ENT * 64) / 256, 256, 0, stream>>>(
            E16, F16 + (size_t)l * 256, ent_attn_vec + (size_t)l * 128,
            hrE, offsE, xout);
    }
    const __half* xfin = xea;  // after l=1, output went to xea

    // 11. output projections
    hgemm((const _Float16*)xfin, Bpe2, ent_proj2_b, nullptr, out, N_ENT, 32, 128, 32, 1);
    gemm64(xr0, rel_proj2_W, 64, rel_proj2_b, out + (size_t)N_ENT * 32, N_REL, 16, 64);
}